// Round 8
// baseline (150.047 us; speedup 1.0000x reference)
//
#include <hip/hip_runtime.h>

// Problem constants
#define BB_   16
#define CIN_  32
#define COUT_ 64
#define TT_   20      // depthwise time extent
#define NSTEP 22      // recurrence steps (pointwise pad grows T 20->22)
#define NPIX  1024    // 32*32
#define HW_   32

typedef float f32x16 __attribute__((ext_vector_type(16)));

// ws layout (in floats)
#define N_DW2   10485760ULL                    // 16*20*32*1024 [slot][ci] transposed
#define OFF_DW2   0ULL
#define OFF_D     (OFF_DW2 + N_DW2)            // 4096 floats
#define OFF_INVN  (OFF_D + 4096ULL)            // 64 floats
#define OFF_CNT   (OFF_INVN + 64ULL)           // 22 uint32
#define WS_FLOATS (OFF_CNT + 32ULL)

#define DWT_BLOCKS (BB_ * TT_ * 8)             // 2560; block 2560 = dmat block

// ---------------------------------------------------------------------------
// K1: FUSED depthwise 3x3x3 conv + transpose. block = (b, t, 4-row h band).
// Stages x[b, all ci, t-1..t+1, band+halo] in LDS (80.6 KB, 2 blocks/CU),
// computes the 27-point stencil with the SAME per-output fmaf order as the
// validated k_depthwise (kt->kh->kw ascending), transposes in-LDS (reusing
// the x buffer) and writes dw2[b][t][h][slot=w+1][ci] in full 128-B lines
// (slot 0 = zeros = built-in left w-pad). Block 2560 = dmat side-block.
// ---------------------------------------------------------------------------
__global__ __launch_bounds__(256)
void k_dwt(const float* __restrict__ x, const float* __restrict__ wdw,
           const float* __restrict__ wpw, float* __restrict__ dw2,
           float* __restrict__ dmat, float* __restrict__ invn,
           unsigned* __restrict__ gcnt) {
    const int blk = blockIdx.x;
    const int tid = threadIdx.x;

    if (blk == DWT_BLOCKS) {                   // ---- dmat block (256 threads)
        __shared__ double S[32];
        if (tid < NSTEP) gcnt[tid] = 0u;
        if (tid < 32) {
            double s = 0.0;
            for (int k = 0; k < 27; ++k) { double v = (double)wdw[tid * 27 + k]; s += v * v; }
            S[tid] = s;
        }
        __syncthreads();
        for (int e = tid; e < 4096; e += 256) {
            const int a = e >> 6, f = e & 63;
            double acc = 0.0;
            for (int ci = 0; ci < 32; ++ci)
                acc += (double)wpw[a * 32 + ci] * (double)wpw[f * 32 + ci] * S[ci];
            dmat[e] = (float)acc;
            if (a == f) invn[a] = (float)(1.0 / (acc + 1e-8));
        }
        return;
    }

    const int hq = blk & 7;                    // 4-row band
    const int bt = blk >> 3;
    const int t  = bt % TT_;
    const int b  = bt / TT_;
    const int h0 = hq * 4;

    // xl[k][ci][r][c]: plane t-1+k, local row r = (h0-1+r), col c = w+1 (0..34)
    __shared__ float xl[3][32][6][35];         // 80640 B; reused for transpose
    float* xp = &xl[0][0][0][0];

    for (int i = tid; i < 3 * 32 * 6 * 35; i += 256) xp[i] = 0.f;
    __syncthreads();

    // load valid rows: 576 rows x 8 float4, coalesced 128-B per row
    for (int i = tid; i < 3 * 32 * 6 * 8; i += 256) {
        const int f4  = i & 7;
        const int row = i >> 3;                // 0..575
        const int r   = row % 6;
        const int ci  = (row / 6) & 31;
        const int k   = row / 192;             // 0..2
        const int tt  = t - 1 + k;
        const int hh  = h0 - 1 + r;
        if (tt >= 0 && tt < TT_ && hh >= 0 && hh < 32) {
            const float4 v = *(const float4*)(x + ((size_t)(b * 32 + ci) * TT_ + tt) * NPIX + hh * 32 + f4 * 4);
            float* d = &xl[k][ci][r][1 + f4 * 4];
            d[0] = v.x; d[1] = v.y; d[2] = v.z; d[3] = v.w;
        }
    }
    __syncthreads();

    // compute: thread = (ci, lh 0..3, wh 0..1) -> 16 outputs along w
    const int ci = tid >> 3;
    const int sub = tid & 7;
    const int lh = sub >> 1;
    const int wh = sub & 1;
    const int w0 = wh * 16;

    float wreg[27];
#pragma unroll
    for (int k = 0; k < 27; ++k) wreg[k] = wdw[ci * 27 + k];

    float acc[16];
#pragma unroll
    for (int j = 0; j < 16; ++j) acc[j] = 0.f;

#pragma unroll
    for (int kt = 0; kt < 3; ++kt) {
#pragma unroll
        for (int kh = 0; kh < 3; ++kh) {
            const float* row = &xl[kt][ci][lh + kh][w0];   // cols w0 .. w0+17
            float r[18];
#pragma unroll
            for (int m = 0; m < 18; ++m) r[m] = row[m];
#pragma unroll
            for (int kw = 0; kw < 3; ++kw) {
                const float wv = wreg[(kt * 3 + kh) * 3 + kw];
#pragma unroll
                for (int j = 0; j < 16; ++j) acc[j] = fmaf(wv, r[j + kw], acc[j]);
            }
        }
    }
    __syncthreads();                 // all xl reads done; reuse as ol[4][32][33]

    // in-LDS transpose: ol[lh][w][ci]
#pragma unroll
    for (int j = 0; j < 16; ++j) xp[(lh * 32 + w0 + j) * 33 + ci] = acc[j];
    __syncthreads();

    // coalesced dw2 write: thread -> 16 consecutive floats (64 B)
    const int lh2 = tid >> 6;                  // 0..3
    const int wp  = (tid & 63) * 16;           // 0..1008
    const int slot = wp >> 5;                  // 0..31
    const int ci0  = wp & 31;                  // 0 or 16
    float4 o[4];
    if (slot == 0) {
#pragma unroll
        for (int q = 0; q < 4; ++q) o[q] = make_float4(0.f, 0.f, 0.f, 0.f);
    } else {
        const float* src = &xp[(lh2 * 32 + (slot - 1)) * 33 + ci0];
#pragma unroll
        for (int q = 0; q < 4; ++q)
            o[q] = make_float4(src[q * 4], src[q * 4 + 1], src[q * 4 + 2], src[q * 4 + 3]);
    }
    float* dst = dw2 + ((size_t)(b * TT_ + t) * 32 + h0 + lh2) * NPIX + slot * 32 + ci0;
#pragma unroll
    for (int q = 0; q < 4; ++q) *(float4*)(dst + q * 4) = o[q];
}

// ---------------------------------------------------------------------------
// K3: ballot-wave fused pointwise conv + recurrence (R5 form, VERBATIM -
// barrier-free t-loop, terminal 64-B-granular bit->float store phase).
// ---------------------------------------------------------------------------
__global__ __launch_bounds__(512)
void k_recur(const float* __restrict__ dw2, const float* __restrict__ wpw,
             const float* __restrict__ dmat, const float* __restrict__ invn_g,
             const float* __restrict__ beta_g, const float* __restrict__ bvec,
             float* __restrict__ out, unsigned* __restrict__ gcnt) {
    const int blk = blockIdx.x;
    const int whalf = blk & 1;
    const int h = (blk >> 1) & 31;
    const int b = blk >> 6;
    const int tid = threadIdx.x;
    const int lane = tid & 63;
    const int co = lane;
    const int wid = __builtin_amdgcn_readfirstlane(tid >> 6);   // 0..7
    const int w0 = whalf * 16 + wid * 2;        // global w of wave's pixel 0

    __shared__ float d_lds[4096];
    __shared__ unsigned long long msk[NSTEP][16];

    for (int i = tid; i < 4096; i += 512) d_lds[i] = dmat[i];
    {
        unsigned long long* mp = &msk[0][0];
        for (int i = tid; i < NSTEP * 16; i += 512) mp[i] = 0ull;
    }

    const float beta_v = beta_g[0];
    const float omb = 1.0f - beta_v;
    const float invn = invn_g[co];
    const float bth  = bvec[co];

    float wa[32];
#pragma unroll
    for (int ci = 0; ci < 32; ++ci) wa[ci] = wpw[co * 32 + ci];

    float mem0 = 0.f, mem1 = 0.f;
    unsigned long long m0p = 0ull, m1p = 0ull;

    // t = 0 plane: all spikes zero (inp=0, mem=0, -b<0). 512 thr x float2 = 4KB.
    {
        const int zco = tid >> 3, zw = (tid & 7) * 2;
        *(float2*)(out + ((size_t)(b * 64 + zco) * NSTEP) * NPIX + h * 32 + whalf * 16 + zw)
            = make_float2(0.f, 0.f);
    }

    __syncthreads();   // d_lds + zeroed bitplanes visible

    // wave-uniform base into dw2 (b, h-1, slots w0..w0+1); valid iff h>=1
    const int base0 = ((b * TT_) * 32 + (h - 1)) * NPIX + w0 * 32;
    const bool hok = (h >= 1);

    f32x16 A0, A1, A2, A3;          // wave-uniform -> SGPRs
    if (hok) {                      // preload step t=1 (plane 0)
        const float* wrow = dw2 + (size_t)base0;
        A0 = *(const f32x16*)(wrow);
        A1 = *(const f32x16*)(wrow + 16);
        A2 = *(const f32x16*)(wrow + 32);
        A3 = *(const f32x16*)(wrow + 48);
    }

    for (int t = 1; t < NSTEP; ++t) {
        float inp0 = 0.f, inp1 = 0.f;
        if (hok && t <= TT_) {      // consume current A set (ci-ascending, bit-exact)
#pragma unroll
            for (int ci = 0; ci < 16; ++ci) {
                inp0 = fmaf(wa[ci], A0[ci], inp0);
                inp1 = fmaf(wa[ci], A2[ci], inp1);
            }
#pragma unroll
            for (int ci = 0; ci < 16; ++ci) {
                inp0 = fmaf(wa[16 + ci], A1[ci], inp0);
                inp1 = fmaf(wa[16 + ci], A3[ci], inp1);
            }
        }
        // reissue loads for step t+1 into the same registers (hidden under tail)
        if (hok && t < TT_) {
            const float* wrow = dw2 + (size_t)base0 + (size_t)t * (32 * NPIX);
            A0 = *(const f32x16*)(wrow);
            A1 = *(const f32x16*)(wrow + 16);
            A2 = *(const f32x16*)(wrow + 32);
            A3 = *(const f32x16*)(wrow + 48);
        }

        // lateral reset from previous step's masks (sparse bit iteration)
        float rst0 = 0.f, rst1 = 0.f;
        unsigned long long mm = m0p;
        while (mm) { const int a = __builtin_ctzll(mm); mm &= mm - 1; rst0 += d_lds[a * 64 + co]; }
        mm = m1p;
        while (mm) { const int a = __builtin_ctzll(mm); mm &= mm - 1; rst1 += d_lds[a * 64 + co]; }

        // membrane update + spike (same expression order as validated rounds)
        const float u0 = (mem0 - rst0) * beta_v;
        mem0 = u0 + inp0 * omb;
        const bool s0 = (mem0 * invn - bth) > 0.f;
        const float u1 = (mem1 - rst1) * beta_v;
        mem1 = u1 + inp1 * omb;
        const bool s1 = (mem1 * invn - bth) > 0.f;

        m0p = __ballot(s0);
        m1p = __ballot(s1);
        const int wl = wid * 2;
        if (lane == 0) { msk[t][wl] = m0p; msk[t][wl + 1] = m1p; }
    }
    __syncthreads();

    // exact per-t spike counts (integer, deterministic)
    if (tid < NSTEP) {
        unsigned c = 0;
        for (int w = 0; w < 16; ++w) c += (unsigned)__popcll(msk[tid][w]);
        if (c) atomicAdd(&gcnt[tid], c);
    }

    // coalesced bit->float stores: 1408 (co,t) rows x 16 w (64B, sector-exact)
    const int wl = tid & 15;
    for (int it = 0; it < 44; ++it) {
        const int r = it * 32 + (tid >> 4);         // 0..1407
        const int tt = r >> 6, cc = r & 63;
        const unsigned long long wv = msk[tt][wl];
        const float sv = (float)((wv >> cc) & 1ull);
        out[((size_t)(b * 64 + cc) * NSTEP + tt) * NPIX + h * 32 + whalf * 16 + wl] = sv;
    }
}

// ---------------------------------------------------------------------------
// K4: losses from exact integer spike counts
// ---------------------------------------------------------------------------
__global__ void k_final(const unsigned* __restrict__ gcnt, float* __restrict__ out,
                        int out_size) {
    if (threadIdx.x == 0 && blockIdx.x == 0) {
        unsigned long long tot = 0; unsigned mx = 0;
        for (int t = 0; t < NSTEP; ++t) { const unsigned c = gcnt[t]; tot += c; if (c > mx) mx = c; }
        const long long nspk = (long long)out_size - 2;          // 23,068,672
        out[out_size - 2] = (float)(0.5 * ((double)tot / (double)nspk));
        out[out_size - 1] = (float)((double)mx / 1048576.0);     // / (B*COUT*H*W)
    }
}

extern "C" void kernel_launch(void* const* d_in, const int* in_sizes, int n_in,
                              void* d_out, int out_size, void* d_ws, size_t ws_size,
                              hipStream_t stream) {
    const float* x    = (const float*)d_in[0];
    const float* wdw  = (const float*)d_in[1];
    const float* wpw  = (const float*)d_in[2];
    const float* beta = (const float*)d_in[3];
    const float* bvec = (const float*)d_in[4];
    float* out = (float*)d_out;
    float* ws  = (float*)d_ws;

    if (ws_size < WS_FLOATS * sizeof(float)) return;

    float* dw2   = ws + OFF_DW2;
    float* dmat  = ws + OFF_D;
    float* invn  = ws + OFF_INVN;
    unsigned* gcnt = (unsigned*)(ws + OFF_CNT);

    k_dwt  <<<DWT_BLOCKS + 1, 256, 0, stream>>>(x, wdw, wpw, dw2, dmat, invn, gcnt);
    k_recur<<<BB_ * HW_ * 2, 512, 0, stream>>>(dw2, wpw, dmat, invn, beta, bvec, out, gcnt);
    k_final<<<1, 64, 0, stream>>>(gcnt, out, out_size);
}

// Round 9
// 102.404 us; speedup vs baseline: 1.4652x; 1.4652x over previous
//
#include <hip/hip_runtime.h>
#include <hip/hip_cooperative_groups.h>

namespace cg = cooperative_groups;

// Problem constants
#define BB_   16
#define CIN_  32
#define COUT_ 64
#define TT_   20      // depthwise time extent
#define NSTEP 22      // recurrence steps (pointwise pad grows T 20->22)
#define NPIX  1024    // 32*32
#define HW_   32

typedef float f32x16 __attribute__((ext_vector_type(16)));

// ws layout (in floats)
#define N_DWOUT 10485760ULL                    // 16*32*20*1024 [ci-major]
#define N_DW2   10485760ULL                    // 16*20*32*1024 [slot][ci] transposed
#define OFF_DWOUT 0ULL
#define OFF_DW2   (OFF_DWOUT + N_DWOUT)
#define OFF_D     (OFF_DW2 + N_DW2)            // 4096 floats
#define OFF_INVN  (OFF_D + 4096ULL)            // 64 floats
#define OFF_CNT   (OFF_INVN + 64ULL)           // 22 uint32
#define WS_FLOATS (OFF_CNT + 32ULL)

#define DW_BLOCKS (BB_ * CIN_ * 4)             // fallback: 2048 + dmat block

// ===========================================================================
// MEGA cooperative kernel: phase A depthwise -> sync -> phase B transpose+dmat
// -> sync -> phase C recurrence (R5 k_recur verbatim) -> sync -> final.
// 1024 blocks x 512 thr = 4 blocks/CU guaranteed by __launch_bounds__(512,8).
// ===========================================================================
__global__ __launch_bounds__(512, 8)
void k_mega(const float* __restrict__ x, const float* __restrict__ wdw,
            const float* __restrict__ wpw, const float* __restrict__ beta_g,
            const float* __restrict__ bvec, float* __restrict__ dwout,
            float* __restrict__ dw2, float* __restrict__ dmat,
            float* __restrict__ invn_g, unsigned* __restrict__ gcnt,
            float* __restrict__ out, int out_size) {
    cg::grid_group grid = cg::this_grid();
    const int blk = blockIdx.x;
    const int tid = threadIdx.x;
    __shared__ __align__(16) char lsd[28560];   // max(phaseA 2x14280, B 4224+, C 19200)

    // ---------------- phase A: depthwise conv (validated stencil, 2 groups) --
    {
        if (blk == 1023 && tid < NSTEP) gcnt[tid] = 0u;   // pre-sync zeroing

        const int grp  = tid >> 8;                 // 0,1
        const int gtid = tid & 255;
        const int tile = blk * 2 + grp;            // 0..2047 == old (b,ci,t4)
        const int t4 = tile & 3;
        const int ci = (tile >> 2) & 31;
        const int b  = tile >> 7;

        float* plbase = (float*)lsd + grp * (3 * 34 * 35);
        for (int i = gtid; i < 3 * 34 * 35; i += 256) plbase[i] = 0.f;

        // weights: ci is wave-uniform -> scalar regs
        const int ciu = __builtin_amdgcn_readfirstlane(ci);
        float w[27];
#pragma unroll
        for (int k = 0; k < 27; ++k) w[k] = wdw[ciu * 27 + k];
        __syncthreads();

        const float* xb = x + (size_t)(b * 32 + ciu) * TT_ * NPIX;
        const int lr = gtid >> 3;            // 0..31 row
        const int lc = (gtid & 7) * 4;       // col group of 4

        auto load_plane = [&](int p, int slot) {
            const float4 v = *(const float4*)(xb + (size_t)p * NPIX + lr * 32 + lc);
            float* d = plbase + slot * 1190 + (1 + lr) * 35 + 1 + lc;
            d[0] = v.x; d[1] = v.y; d[2] = v.z; d[3] = v.w;
        };
        auto zero_plane = [&](int slot) {
            float* d = plbase + slot * 1190 + (1 + lr) * 35 + 1 + lc;
#pragma unroll
            for (int j = 0; j < 4; ++j) d[j] = 0.f;
        };

        const int T0 = t4 * 5;
        if (T0 > 0) load_plane(T0 - 1, (T0 - 1) % 3);
        load_plane(T0, T0 % 3);

        const int hd = lr, wd0 = lc;
        for (int t = T0; t < T0 + 5; ++t) {
            __syncthreads();
            const int pnext = t + 1;
            if (pnext < TT_) load_plane(pnext, pnext % 3);
            else             zero_plane(pnext % 3);
            __syncthreads();

            const int sm1 = (t + 2) % 3, s0 = t % 3, sp1 = (t + 1) % 3;
            float acc[4] = {0.f, 0.f, 0.f, 0.f};
#pragma unroll
            for (int kt = 0; kt < 3; ++kt) {
                const int slot = (kt == 0) ? sm1 : (kt == 1) ? s0 : sp1;
#pragma unroll
                for (int kh = 0; kh < 3; ++kh) {
                    const float* row = plbase + slot * 1190 + (hd + kh) * 35 + wd0;
                    float r[6];
#pragma unroll
                    for (int m = 0; m < 6; ++m) r[m] = row[m];
#pragma unroll
                    for (int kw = 0; kw < 3; ++kw) {
                        const float wv = w[(kt * 3 + kh) * 3 + kw];
#pragma unroll
                        for (int j = 0; j < 4; ++j) acc[j] = fmaf(wv, r[j + kw], acc[j]);
                    }
                }
            }
            float* dst = dwout + ((size_t)(b * 32 + ciu) * TT_ + t) * NPIX + hd * 32 + wd0;
            *(float4*)dst = make_float4(acc[0], acc[1], acc[2], acc[3]);
        }
    }
    grid.sync();

    // ---------------- phase B: transpose dwout -> dw2 (+ dmat in block 1023) -
    {
        float* lt = (float*)lsd;                     // [32][33]
        const int wsrc = tid & 31, cg16 = tid >> 5;  // 0..15
        for (int tile = blk; tile < BB_ * TT_ * 8; tile += 1024) {
            const int hq = tile & 7;
            const int bt = tile >> 3;
            const int t  = bt % TT_;
            const int b  = bt / TT_;
            for (int hh = 0; hh < 4; ++hh) {
                const int h = hq * 4 + hh;
#pragma unroll
                for (int cc = 0; cc < 2; ++cc) {
                    const int ci = cc * 16 + cg16;
                    lt[wsrc * 33 + ci] =
                        dwout[((size_t)(b * 32 + ci) * TT_ + t) * NPIX + h * 32 + wsrc];
                }
                __syncthreads();
                float* drow = dw2 + ((size_t)(b * TT_ + t) * 32 + h) * NPIX;
#pragma unroll
                for (int ss = 0; ss < 2; ++ss) {
                    const int slot = ss * 16 + cg16;
                    drow[slot * 32 + wsrc] = (slot == 0) ? 0.f : lt[(slot - 1) * 33 + wsrc];
                }
                __syncthreads();
            }
        }
        if (blk == 1023) {                           // fp64 lateral matrix
            double* S = (double*)(lsd + 8192);
            if (tid < 32) {
                double s = 0.0;
                for (int k = 0; k < 27; ++k) { double v = (double)wdw[tid * 27 + k]; s += v * v; }
                S[tid] = s;
            }
            __syncthreads();
            for (int e = tid; e < 4096; e += 512) {
                const int a = e >> 6, f = e & 63;
                double acc = 0.0;
                for (int ci = 0; ci < 32; ++ci)
                    acc += (double)wpw[a * 32 + ci] * (double)wpw[f * 32 + ci] * S[ci];
                dmat[e] = (float)acc;
                if (a == f) invn_g[a] = (float)(1.0 / (acc + 1e-8));
            }
        }
    }
    grid.sync();

    // ---------------- phase C: R5 k_recur VERBATIM ---------------------------
    {
        const int whalf = blk & 1;
        const int h = (blk >> 1) & 31;
        const int b = blk >> 6;
        const int lane = tid & 63;
        const int co = lane;
        const int wid = __builtin_amdgcn_readfirstlane(tid >> 6);   // 0..7
        const int w0 = whalf * 16 + wid * 2;

        float* d_lds = (float*)lsd;                                  // 16384 B
        unsigned long long (*msk)[16] = (unsigned long long (*)[16])(lsd + 16384);

        for (int i = tid; i < 4096; i += 512) d_lds[i] = dmat[i];
        {
            unsigned long long* mp = &msk[0][0];
            for (int i = tid; i < NSTEP * 16; i += 512) mp[i] = 0ull;
        }

        const float beta_v = beta_g[0];
        const float omb = 1.0f - beta_v;
        const float invn = invn_g[co];
        const float bth  = bvec[co];

        float wa[32];
#pragma unroll
        for (int ci = 0; ci < 32; ++ci) wa[ci] = wpw[co * 32 + ci];

        float mem0 = 0.f, mem1 = 0.f;
        unsigned long long m0p = 0ull, m1p = 0ull;

        {   // t = 0 plane: all spikes zero
            const int zco = tid >> 3, zw = (tid & 7) * 2;
            *(float2*)(out + ((size_t)(b * 64 + zco) * NSTEP) * NPIX + h * 32 + whalf * 16 + zw)
                = make_float2(0.f, 0.f);
        }
        __syncthreads();

        const int base0 = ((b * TT_) * 32 + (h - 1)) * NPIX + w0 * 32;
        const bool hok = (h >= 1);

        f32x16 A0, A1, A2, A3;
        if (hok) {
            const float* wrow = dw2 + (size_t)base0;
            A0 = *(const f32x16*)(wrow);
            A1 = *(const f32x16*)(wrow + 16);
            A2 = *(const f32x16*)(wrow + 32);
            A3 = *(const f32x16*)(wrow + 48);
        }

        for (int t = 1; t < NSTEP; ++t) {
            float inp0 = 0.f, inp1 = 0.f;
            if (hok && t <= TT_) {
#pragma unroll
                for (int ci = 0; ci < 16; ++ci) {
                    inp0 = fmaf(wa[ci], A0[ci], inp0);
                    inp1 = fmaf(wa[ci], A2[ci], inp1);
                }
#pragma unroll
                for (int ci = 0; ci < 16; ++ci) {
                    inp0 = fmaf(wa[16 + ci], A1[ci], inp0);
                    inp1 = fmaf(wa[16 + ci], A3[ci], inp1);
                }
            }
            if (hok && t < TT_) {
                const float* wrow = dw2 + (size_t)base0 + (size_t)t * (32 * NPIX);
                A0 = *(const f32x16*)(wrow);
                A1 = *(const f32x16*)(wrow + 16);
                A2 = *(const f32x16*)(wrow + 32);
                A3 = *(const f32x16*)(wrow + 48);
            }

            float rst0 = 0.f, rst1 = 0.f;
            unsigned long long mm = m0p;
            while (mm) { const int a = __builtin_ctzll(mm); mm &= mm - 1; rst0 += d_lds[a * 64 + co]; }
            mm = m1p;
            while (mm) { const int a = __builtin_ctzll(mm); mm &= mm - 1; rst1 += d_lds[a * 64 + co]; }

            const float u0 = (mem0 - rst0) * beta_v;
            mem0 = u0 + inp0 * omb;
            const bool s0 = (mem0 * invn - bth) > 0.f;
            const float u1 = (mem1 - rst1) * beta_v;
            mem1 = u1 + inp1 * omb;
            const bool s1 = (mem1 * invn - bth) > 0.f;

            m0p = __ballot(s0);
            m1p = __ballot(s1);
            const int wl = wid * 2;
            if (lane == 0) { msk[t][wl] = m0p; msk[t][wl + 1] = m1p; }
        }
        __syncthreads();

        if (tid < NSTEP) {
            unsigned c = 0;
            for (int w = 0; w < 16; ++w) c += (unsigned)__popcll(msk[tid][w]);
            if (c) atomicAdd(&gcnt[tid], c);
        }

        const int wl = tid & 15;
        for (int it = 0; it < 44; ++it) {
            const int r = it * 32 + (tid >> 4);
            const int tt = r >> 6, cc = r & 63;
            const unsigned long long wv = msk[tt][wl];
            const float sv = (float)((wv >> cc) & 1ull);
            out[((size_t)(b * 64 + cc) * NSTEP + tt) * NPIX + h * 32 + whalf * 16 + wl] = sv;
        }
    }
    grid.sync();

    // ---------------- final: losses from exact integer spike counts ---------
    if (blk == 0 && tid == 0) {
        unsigned long long tot = 0; unsigned mx = 0;
        for (int t = 0; t < NSTEP; ++t) { const unsigned c = gcnt[t]; tot += c; if (c > mx) mx = c; }
        const long long nspk = (long long)out_size - 2;          // 23,068,672
        out[out_size - 2] = (float)(0.5 * ((double)tot / (double)nspk));
        out[out_size - 1] = (float)((double)mx / 1048576.0);     // / (B*COUT*H*W)
    }
}

// ===========================================================================
// FALLBACK path: R5 kernels verbatim (used if cooperative launch unavailable)
// ===========================================================================
__global__ __launch_bounds__(128)
void k_depthwise(const float* __restrict__ x, const float* __restrict__ wdw,
                 const float* __restrict__ wpw, float* __restrict__ dwout,
                 float* __restrict__ dmat, float* __restrict__ invn,
                 unsigned* __restrict__ gcnt) {
    const int blk = blockIdx.x;
    const int tid = threadIdx.x;

    if (blk == DW_BLOCKS) {
        __shared__ double S[32];
        if (tid < NSTEP) gcnt[tid] = 0u;
        if (tid < 32) {
            double s = 0.0;
            for (int k = 0; k < 27; ++k) { double v = (double)wdw[tid * 27 + k]; s += v * v; }
            S[tid] = s;
        }
        __syncthreads();
        for (int e = tid; e < 4096; e += 128) {
            const int a = e >> 6, f = e & 63;
            double acc = 0.0;
            for (int ci = 0; ci < 32; ++ci)
                acc += (double)wpw[a * 32 + ci] * (double)wpw[f * 32 + ci] * S[ci];
            dmat[e] = (float)acc;
            if (a == f) invn[a] = (float)(1.0 / (acc + 1e-8));
        }
        return;
    }

    const int t4 = blk & 3;
    const int ci = (blk >> 2) & 31;
    const int b  = blk >> 7;
    __shared__ float pl[3][34][35];

    float w[27];
#pragma unroll
    for (int k = 0; k < 27; ++k) w[k] = wdw[ci * 27 + k];

    for (int i = tid; i < 3 * 34 * 35; i += 128) (&pl[0][0][0])[i] = 0.f;
    __syncthreads();

    const float* xb = x + (size_t)(b * 32 + ci) * TT_ * NPIX;
    const int lr = tid >> 2;
    const int lc = (tid & 3) * 8;

    auto load_plane = [&](int p, int slot) {
        const float* s = xb + (size_t)p * NPIX + lr * 32 + lc;
        float4 v0 = *(const float4*)s;
        float4 v1 = *(const float4*)(s + 4);
        float* d = &pl[slot][1 + lr][1 + lc];
        d[0] = v0.x; d[1] = v0.y; d[2] = v0.z; d[3] = v0.w;
        d[4] = v1.x; d[5] = v1.y; d[6] = v1.z; d[7] = v1.w;
    };
    auto zero_plane = [&](int slot) {
        float* d = &pl[slot][1 + lr][1 + lc];
#pragma unroll
        for (int j = 0; j < 8; ++j) d[j] = 0.f;
    };

    const int T0 = t4 * 5;
    if (T0 > 0) load_plane(T0 - 1, (T0 - 1) % 3);
    load_plane(T0, T0 % 3);

    const int hd = lr, wd0 = lc;
    const float* base = &pl[0][0][0];

    for (int t = T0; t < T0 + 5; ++t) {
        __syncthreads();
        const int pnext = t + 1;
        if (pnext < TT_) load_plane(pnext, pnext % 3);
        else             zero_plane(pnext % 3);
        __syncthreads();

        const int sm1 = (t + 2) % 3, s0 = t % 3, sp1 = (t + 1) % 3;
        float acc[8] = {0.f,0.f,0.f,0.f,0.f,0.f,0.f,0.f};
#pragma unroll
        for (int kt = 0; kt < 3; ++kt) {
            const int slot = (kt == 0) ? sm1 : (kt == 1) ? s0 : sp1;
            const float* Pp = base + slot * (34 * 35);
#pragma unroll
            for (int kh = 0; kh < 3; ++kh) {
                const float* row = Pp + (hd + kh) * 35 + wd0;
                float r[10];
#pragma unroll
                for (int m = 0; m < 10; ++m) r[m] = row[m];
#pragma unroll
                for (int kw = 0; kw < 3; ++kw) {
                    const float wv = w[(kt * 3 + kh) * 3 + kw];
#pragma unroll
                    for (int j = 0; j < 8; ++j) acc[j] = fmaf(wv, r[j + kw], acc[j]);
                }
            }
        }
        float* dst = dwout + ((size_t)(b * 32 + ci) * TT_ + t) * NPIX + hd * 32 + wd0;
        *(float4*)dst       = make_float4(acc[0], acc[1], acc[2], acc[3]);
        *(float4*)(dst + 4) = make_float4(acc[4], acc[5], acc[6], acc[7]);
    }
}

__global__ __launch_bounds__(256)
void k_transpose(const float* __restrict__ dwout, float* __restrict__ dw2) {
    const int blk = blockIdx.x;
    const int hq = blk & 7;
    const int bt = blk >> 3;
    const int t  = bt % 20;
    const int b  = bt / 20;
    const int tid = threadIdx.x;
    __shared__ float lt[32][33];
    const int wsrc = tid & 31, cgi = tid >> 5;

    for (int hh = 0; hh < 4; ++hh) {
        const int h = hq * 4 + hh;
#pragma unroll
        for (int cc = 0; cc < 4; ++cc) {
            const int ci = cc * 8 + cgi;
            lt[wsrc][ci] = dwout[((size_t)(b * 32 + ci) * TT_ + t) * NPIX + h * 32 + wsrc];
        }
        __syncthreads();
        float* drow = dw2 + ((size_t)(b * TT_ + t) * 32 + h) * NPIX;
#pragma unroll
        for (int ss = 0; ss < 4; ++ss) {
            const int slot = ss * 8 + cgi;
            drow[slot * 32 + wsrc] = (slot == 0) ? 0.f : lt[slot - 1][wsrc];
        }
        __syncthreads();
    }
}

__global__ __launch_bounds__(512)
void k_recur(const float* __restrict__ dw2, const float* __restrict__ wpw,
             const float* __restrict__ dmat, const float* __restrict__ invn_g,
             const float* __restrict__ beta_g, const float* __restrict__ bvec,
             float* __restrict__ out, unsigned* __restrict__ gcnt) {
    const int blk = blockIdx.x;
    const int whalf = blk & 1;
    const int h = (blk >> 1) & 31;
    const int b = blk >> 6;
    const int tid = threadIdx.x;
    const int lane = tid & 63;
    const int co = lane;
    const int wid = __builtin_amdgcn_readfirstlane(tid >> 6);
    const int w0 = whalf * 16 + wid * 2;

    __shared__ float d_lds[4096];
    __shared__ unsigned long long msk[NSTEP][16];

    for (int i = tid; i < 4096; i += 512) d_lds[i] = dmat[i];
    {
        unsigned long long* mp = &msk[0][0];
        for (int i = tid; i < NSTEP * 16; i += 512) mp[i] = 0ull;
    }

    const float beta_v = beta_g[0];
    const float omb = 1.0f - beta_v;
    const float invn = invn_g[co];
    const float bth  = bvec[co];

    float wa[32];
#pragma unroll
    for (int ci = 0; ci < 32; ++ci) wa[ci] = wpw[co * 32 + ci];

    float mem0 = 0.f, mem1 = 0.f;
    unsigned long long m0p = 0ull, m1p = 0ull;

    {
        const int zco = tid >> 3, zw = (tid & 7) * 2;
        *(float2*)(out + ((size_t)(b * 64 + zco) * NSTEP) * NPIX + h * 32 + whalf * 16 + zw)
            = make_float2(0.f, 0.f);
    }
    __syncthreads();

    const int base0 = ((b * TT_) * 32 + (h - 1)) * NPIX + w0 * 32;
    const bool hok = (h >= 1);

    f32x16 A0, A1, A2, A3;
    if (hok) {
        const float* wrow = dw2 + (size_t)base0;
        A0 = *(const f32x16*)(wrow);
        A1 = *(const f32x16*)(wrow + 16);
        A2 = *(const f32x16*)(wrow + 32);
        A3 = *(const f32x16*)(wrow + 48);
    }

    for (int t = 1; t < NSTEP; ++t) {
        float inp0 = 0.f, inp1 = 0.f;
        if (hok && t <= TT_) {
#pragma unroll
            for (int ci = 0; ci < 16; ++ci) {
                inp0 = fmaf(wa[ci], A0[ci], inp0);
                inp1 = fmaf(wa[ci], A2[ci], inp1);
            }
#pragma unroll
            for (int ci = 0; ci < 16; ++ci) {
                inp0 = fmaf(wa[16 + ci], A1[ci], inp0);
                inp1 = fmaf(wa[16 + ci], A3[ci], inp1);
            }
        }
        if (hok && t < TT_) {
            const float* wrow = dw2 + (size_t)base0 + (size_t)t * (32 * NPIX);
            A0 = *(const f32x16*)(wrow);
            A1 = *(const f32x16*)(wrow + 16);
            A2 = *(const f32x16*)(wrow + 32);
            A3 = *(const f32x16*)(wrow + 48);
        }

        float rst0 = 0.f, rst1 = 0.f;
        unsigned long long mm = m0p;
        while (mm) { const int a = __builtin_ctzll(mm); mm &= mm - 1; rst0 += d_lds[a * 64 + co]; }
        mm = m1p;
        while (mm) { const int a = __builtin_ctzll(mm); mm &= mm - 1; rst1 += d_lds[a * 64 + co]; }

        const float u0 = (mem0 - rst0) * beta_v;
        mem0 = u0 + inp0 * omb;
        const bool s0 = (mem0 * invn - bth) > 0.f;
        const float u1 = (mem1 - rst1) * beta_v;
        mem1 = u1 + inp1 * omb;
        const bool s1 = (mem1 * invn - bth) > 0.f;

        m0p = __ballot(s0);
        m1p = __ballot(s1);
        const int wl = wid * 2;
        if (lane == 0) { msk[t][wl] = m0p; msk[t][wl + 1] = m1p; }
    }
    __syncthreads();

    if (tid < NSTEP) {
        unsigned c = 0;
        for (int w = 0; w < 16; ++w) c += (unsigned)__popcll(msk[tid][w]);
        if (c) atomicAdd(&gcnt[tid], c);
    }

    const int wl = tid & 15;
    for (int it = 0; it < 44; ++it) {
        const int r = it * 32 + (tid >> 4);
        const int tt = r >> 6, cc = r & 63;
        const unsigned long long wv = msk[tt][wl];
        const float sv = (float)((wv >> cc) & 1ull);
        out[((size_t)(b * 64 + cc) * NSTEP + tt) * NPIX + h * 32 + whalf * 16 + wl] = sv;
    }
}

__global__ void k_final(const unsigned* __restrict__ gcnt, float* __restrict__ out,
                        int out_size) {
    if (threadIdx.x == 0 && blockIdx.x == 0) {
        unsigned long long tot = 0; unsigned mx = 0;
        for (int t = 0; t < NSTEP; ++t) { const unsigned c = gcnt[t]; tot += c; if (c > mx) mx = c; }
        const long long nspk = (long long)out_size - 2;
        out[out_size - 2] = (float)(0.5 * ((double)tot / (double)nspk));
        out[out_size - 1] = (float)((double)mx / 1048576.0);
    }
}

extern "C" void kernel_launch(void* const* d_in, const int* in_sizes, int n_in,
                              void* d_out, int out_size, void* d_ws, size_t ws_size,
                              hipStream_t stream) {
    const float* x    = (const float*)d_in[0];
    const float* wdw  = (const float*)d_in[1];
    const float* wpw  = (const float*)d_in[2];
    const float* beta = (const float*)d_in[3];
    const float* bvec = (const float*)d_in[4];
    float* out = (float*)d_out;
    float* ws  = (float*)d_ws;

    if (ws_size < WS_FLOATS * sizeof(float)) return;

    float* dwout = ws + OFF_DWOUT;
    float* dw2   = ws + OFF_DW2;
    float* dmat  = ws + OFF_D;
    float* invn  = ws + OFF_INVN;
    unsigned* gcnt = (unsigned*)(ws + OFF_CNT);

    // Prefer single cooperative launch (kills ~35us of inter-launch drain).
    int maxb = 0;
    bool coop = (hipOccupancyMaxActiveBlocksPerMultiprocessor(
                     &maxb, (const void*)k_mega, 512, 0) == hipSuccess) && (maxb >= 4);
    if (coop) {
        void* args[] = {(void*)&x, (void*)&wdw, (void*)&wpw, (void*)&beta, (void*)&bvec,
                        (void*)&dwout, (void*)&dw2, (void*)&dmat, (void*)&invn,
                        (void*)&gcnt, (void*)&out, (void*)&out_size};
        if (hipLaunchCooperativeKernel((const void*)k_mega, dim3(1024), dim3(512),
                                       args, 0, stream) != hipSuccess)
            coop = false;
    }
    if (!coop) {   // R5 fallback path
        k_depthwise<<<DW_BLOCKS + 1, 128, 0, stream>>>(x, wdw, wpw, dwout, dmat, invn, gcnt);
        k_transpose<<<BB_ * TT_ * 8, 256, 0, stream>>>(dwout, dw2);
        k_recur    <<<BB_ * HW_ * 2, 512, 0, stream>>>(dw2, wpw, dmat, invn, beta, bvec, out, gcnt);
        k_final    <<<1, 64, 0, stream>>>(gcnt, out, out_size);
    }
}